// Round 4
// baseline (380.413 us; speedup 1.0000x reference)
//
#include <hip/hip_runtime.h>
#include <math.h>

#define DIMD 1024
#define SEQ  2048
#define BATCH 8
#define ROWS (BATCH * SEQ)   // 16384

#define MF 1152              // folded cos-GEMM M (rows s=0..1151, need 0..1024)
#define KF 1088              // folded cos-GEMM K (t=0..1024 + pad)

typedef __attribute__((ext_vector_type(8))) short bf16x8;
typedef __attribute__((ext_vector_type(4))) float f32x4;
typedef __attribute__((ext_vector_type(8))) unsigned short ushort8;

// ---------------- helpers ----------------
__device__ __forceinline__ unsigned short f2bf(float f) {
    unsigned u = __float_as_uint(f);
    unsigned r = (u + 0x7FFFu + ((u >> 16) & 1u)) >> 16;
    return (unsigned short)r;
}
__device__ __forceinline__ float bf2f(unsigned short h) {
    return __uint_as_float(((unsigned)h) << 16);
}
__device__ __forceinline__ void gl_lds16(const void* g, void* l) {
    __builtin_amdgcn_global_load_lds(
        (const __attribute__((address_space(1))) unsigned int*)g,
        (__attribute__((address_space(3))) unsigned int*)l, 16, 0, 0);
}

// ---------------------------------------------------------------------------
// Precompute kernels
// ---------------------------------------------------------------------------

// Acos[s][t] = bf16(cos(pi*((s*t)&2047)/1024)) for t<=1024, else 0.  MF x KF
__global__ __launch_bounds__(256) void build_acos(unsigned short* __restrict__ Acos) {
    int s = blockIdx.x;                       // 0..MF-1
    for (int t = threadIdx.x; t < KF; t += 256) {
        float c = 0.0f;
        if (t <= 1024) {
            int prod = (s * t) & (SEQ - 1);
            c = cospif((float)prod * (1.0f / 1024.0f));
        }
        Acos[(size_t)s * KF + t] = f2bf(c);
    }
}

// Xe[n = b*1024+d][t] = bf16( x[b,t,rev(d)] + x[b,2048-t,rev(d)] ) (folded)
//   t=0: x[b,0,rd];  t=1024: x[b,1024,rd];  t>1024: 0.      8192 x KF
__global__ __launch_bounds__(256) void build_xe(const float* __restrict__ x,
                                                unsigned short* __restrict__ Xe) {
    int lane = threadIdx.x & 63;
    int oct  = threadIdx.x >> 6;
    int n = blockIdx.x * 64 + lane;           // 0..8191
    int b = n >> 10, d = n & 1023;
    int rd = (DIMD - d) & (DIMD - 1);
    int t0 = blockIdx.y * 32 + oct * 8;       // 0..KF-8
    const float* xb = x + (size_t)b * SEQ * DIMD + rd;
    ushort8 tmp;
    #pragma unroll
    for (int j = 0; j < 8; ++j) {
        int t = t0 + j;
        float v;
        if (t == 0)          v = xb[0];
        else if (t < 1024)   v = xb[(size_t)t * DIMD] + xb[(size_t)(2048 - t) * DIMD];
        else if (t == 1024)  v = xb[(size_t)1024 * DIMD];
        else                 v = 0.0f;
        tmp[j] = f2bf(v);
    }
    *(ushort8*)&Xe[(size_t)n * KF + t0] = tmp;
}

// Wt[n][k] = bf16(W[k][n]),  1024 x 1024
__global__ __launch_bounds__(256) void pack_wt(const float* __restrict__ W,
                                               unsigned short* __restrict__ Wt) {
    int lane = threadIdx.x & 63;
    int oct = threadIdx.x >> 6;
    int n = blockIdx.x * 64 + lane;
    int k0 = blockIdx.y * 32 + oct * 8;
    ushort8 tmp;
    #pragma unroll
    for (int j = 0; j < 8; ++j) tmp[j] = f2bf(W[(size_t)(k0 + j) * DIMD + n]);
    *(ushort8*)&Wt[(size_t)n * DIMD + k0] = tmp;
}

// ---------------------------------------------------------------------------
// MFMA GEMM: C[M x N] = A[M x K] @ B^T[N x K]   (bf16 in, fp32 acc)
// 128x128 tile, BK=64, 256 threads = 4 waves (2x2 of 64x64 each)
// MODE 0 (cos): y_bf16[row s and mirror 2048-s] = bf16(x + 1024*acc)
// MODE 1 (ff1): h_bf16[row*ldc+col] = bf16(gelu(acc + bias[col]))  [XCD swizzle]
// MODE 2 (ff2): out_f32[row*ldc+col] = (acc + bias[col]) * mask[row] [XCD swizzle]
// ---------------------------------------------------------------------------
template <int MODE>
__global__ __launch_bounds__(256) void gemm_bt(const unsigned short* __restrict__ A,
                                               const unsigned short* __restrict__ B,
                                               int K, int lda, int ldb, int ldc,
                                               const float* __restrict__ xres,
                                               const float* __restrict__ bias,
                                               const float* __restrict__ mask,
                                               void* __restrict__ outp) {
    __shared__ unsigned short As[128 * 64];
    __shared__ unsigned short Bs[128 * 64];

    const int tid = threadIdx.x;
    const int lane = tid & 63;
    const int wv = tid >> 6;
    const int wm = wv & 1;
    const int wn = wv >> 1;
    const int fr = lane & 15;
    const int quad = lane >> 4;

    int bx = blockIdx.x, by = blockIdx.y;
    if (MODE != 0) {
        // XCD-aware swizzle: grid is (8, 128); linear = bx + 8*by; XCD = lin&7.
        // Give XCD c the m-tiles {8g+c} so its L2 re-uses each A-tile across
        // all 8 n-tiles (working set 6 MB instead of 32 MB).
        int lin = bx + 8 * by;
        int c = lin & 7;
        int g = lin >> 3;          // 0..127
        bx = g & 7;                // n-tile
        by = (g >> 3) * 8 + c;     // m-tile
    }
    const int m0 = by * 128;
    const int n0 = bx * 128;

    const int st_row = (lane >> 3);          // 0..7 within chunk
    const int st_col = (lane & 7) * 8;       // element offset within row

    f32x4 acc[4][4] = {};

    for (int k0 = 0; k0 < K; k0 += 64) {
        __syncthreads();
        #pragma unroll
        for (int i = 0; i < 4; ++i) {
            int chunk = wv * 4 + i;          // 0..15
            int ar = m0 + chunk * 8 + st_row;
            int br = n0 + chunk * 8 + st_row;
            gl_lds16(&A[(size_t)ar * lda + k0 + st_col], &As[chunk * 512]);
            gl_lds16(&B[(size_t)br * ldb + k0 + st_col], &Bs[chunk * 512]);
        }
        __syncthreads();

        #pragma unroll
        for (int ks = 0; ks < 2; ++ks) {
            bf16x8 af[4], bfv[4];
            #pragma unroll
            for (int i = 0; i < 4; ++i)
                af[i] = *(const bf16x8*)&As[(wm * 64 + i * 16 + fr) * 64 + ks * 32 + quad * 8];
            #pragma unroll
            for (int j = 0; j < 4; ++j)
                bfv[j] = *(const bf16x8*)&Bs[(wn * 64 + j * 16 + fr) * 64 + ks * 32 + quad * 8];
            #pragma unroll
            for (int i = 0; i < 4; ++i)
                #pragma unroll
                for (int j = 0; j < 4; ++j)
                    acc[i][j] = __builtin_amdgcn_mfma_f32_16x16x32_bf16(af[i], bfv[j], acc[i][j], 0, 0, 0);
        }
    }

    // epilogue: row = m0 + wm*64 + i*16 + quad*4 + r ; col = n0 + wn*64 + j*16 + fr
    #pragma unroll
    for (int i = 0; i < 4; ++i) {
        int rowb = m0 + wm * 64 + i * 16 + quad * 4;
        #pragma unroll
        for (int j = 0; j < 4; ++j) {
            int col = n0 + wn * 64 + j * 16 + fr;
            #pragma unroll
            for (int r = 0; r < 4; ++r) {
                float v = acc[i][j][r];
                int row = rowb + r;
                if (MODE == 0) {
                    int s = row;
                    if (s <= 1024) {
                        int b = col >> 10, d = col & 1023;
                        unsigned short* y = (unsigned short*)outp;
                        size_t i1 = ((size_t)b * SEQ + s) * DIMD + d;
                        y[i1] = f2bf(xres[i1] + 1024.0f * v);
                        if (s >= 1 && s <= 1023) {
                            size_t i2 = ((size_t)b * SEQ + (2048 - s)) * DIMD + d;
                            y[i2] = f2bf(xres[i2] + 1024.0f * v);
                        }
                    }
                } else if (MODE == 1) {
                    v += bias[col];
                    v = 0.5f * v * (1.0f + erff(v * 0.70710678118654752f));
                    ((unsigned short*)outp)[(size_t)row * ldc + col] = f2bf(v);
                } else {
                    v += bias[col];
                    v *= mask[row];
                    ((float*)outp)[(size_t)row * ldc + col] = v;
                }
            }
        }
    }
}

// ---------------------------------------------------------------------------
// LayerNorm over bf16 y (1024), write bf16 t.  One block per row.
// ---------------------------------------------------------------------------
__global__ __launch_bounds__(256) void ln_bf(const unsigned short* __restrict__ y,
                                             const float* __restrict__ g,
                                             const float* __restrict__ beta,
                                             unsigned short* __restrict__ t) {
    const int row = blockIdx.x;
    ushort4 raw = ((const ushort4*)(y + (size_t)row * DIMD))[threadIdx.x];
    float v0 = bf2f(raw.x), v1 = bf2f(raw.y), v2 = bf2f(raw.z), v3 = bf2f(raw.w);

    __shared__ float red[4];
    const int wave = threadIdx.x >> 6;
    const int lane = threadIdx.x & 63;

    float sm = v0 + v1 + v2 + v3;
    #pragma unroll
    for (int off = 32; off > 0; off >>= 1) sm += __shfl_down(sm, off, 64);
    if (lane == 0) red[wave] = sm;
    __syncthreads();
    const float mean = (red[0] + red[1] + red[2] + red[3]) * (1.0f / DIMD);

    float dx0 = v0 - mean, dx1 = v1 - mean, dx2 = v2 - mean, dx3 = v3 - mean;
    float q = dx0 * dx0 + dx1 * dx1 + dx2 * dx2 + dx3 * dx3;
    __syncthreads();
    #pragma unroll
    for (int off = 32; off > 0; off >>= 1) q += __shfl_down(q, off, 64);
    if (lane == 0) red[wave] = q;
    __syncthreads();
    const float var = (red[0] + red[1] + red[2] + red[3]) * (1.0f / DIMD);
    const float rstd = rsqrtf(var + 1e-5f);

    float4 g4 = ((const float4*)g)[threadIdx.x];
    float4 b4 = ((const float4*)beta)[threadIdx.x];
    ushort4 o;
    o.x = f2bf(dx0 * rstd * g4.x + b4.x);
    o.y = f2bf(dx1 * rstd * g4.y + b4.y);
    o.z = f2bf(dx2 * rstd * g4.z + b4.z);
    o.w = f2bf(dx3 * rstd * g4.w + b4.w);
    ((ushort4*)(t + (size_t)row * DIMD))[threadIdx.x] = o;
}

// ===========================================================================
// Fallback fp32 path (round-1 kernels) for small workspace
// ===========================================================================
#define BM 64
#define BN 64
#define BK 16

__global__ __launch_bounds__(256) void fft_cos_kernel(const float* __restrict__ x,
                                                      float* __restrict__ y) {
    __shared__ float tab[SEQ];
    __shared__ float As[BM][BK + 1];
    __shared__ float Bs[BK][BN + 1];
    const int tid = threadIdx.x;
    const int b = blockIdx.z;
    const int s0 = blockIdx.y * BM;
    const int n0 = blockIdx.x * BN;
    for (int i = tid; i < SEQ; i += 256) tab[i] = cospif((float)i * (1.0f / 1024.0f));
    const int tx = tid & 15;
    const int ty = tid >> 4;
    float acc[4][4] = {};
    const float* Xb = x + (size_t)b * SEQ * DIMD;
    for (int k0 = 0; k0 < SEQ; k0 += BK) {
        __syncthreads();
        for (int f = tid; f < BM * BK; f += 256) {
            int i = f / BK, k = f % BK;
            int prod = (s0 + i) * (k0 + k);
            As[i][k] = tab[prod & (SEQ - 1)];
        }
        for (int f = tid; f < BK * BN; f += 256) {
            int k = f / BN, j = f % BN;
            int d = n0 + j;
            int rd = (DIMD - d) & (DIMD - 1);
            Bs[k][j] = Xb[(size_t)(k0 + k) * DIMD + rd];
        }
        __syncthreads();
        #pragma unroll
        for (int k = 0; k < BK; ++k) {
            float a[4], bv[4];
            #pragma unroll
            for (int i = 0; i < 4; ++i) a[i] = As[ty * 4 + i][k];
            #pragma unroll
            for (int j = 0; j < 4; ++j) bv[j] = Bs[k][tx * 4 + j];
            #pragma unroll
            for (int i = 0; i < 4; ++i)
                #pragma unroll
                for (int j = 0; j < 4; ++j) acc[i][j] += a[i] * bv[j];
        }
    }
    #pragma unroll
    for (int i = 0; i < 4; ++i) {
        int s = s0 + ty * 4 + i;
        #pragma unroll
        for (int j = 0; j < 4; ++j) {
            int d = n0 + tx * 4 + j;
            y[((size_t)b * SEQ + s) * DIMD + d] = Xb[(size_t)s * DIMD + d] + 1024.0f * acc[i][j];
        }
    }
}

__global__ __launch_bounds__(256) void ln_kernel(float* __restrict__ y,
                                                 const float* __restrict__ g,
                                                 const float* __restrict__ beta) {
    const int row = blockIdx.x;
    float4* p = (float4*)(y + (size_t)row * DIMD);
    float4 v = p[threadIdx.x];
    __shared__ float red[4];
    const int wave = threadIdx.x >> 6;
    const int lane = threadIdx.x & 63;
    float s = v.x + v.y + v.z + v.w;
    #pragma unroll
    for (int off = 32; off > 0; off >>= 1) s += __shfl_down(s, off, 64);
    if (lane == 0) red[wave] = s;
    __syncthreads();
    const float mean = (red[0] + red[1] + red[2] + red[3]) * (1.0f / DIMD);
    float dx0 = v.x - mean, dx1 = v.y - mean, dx2 = v.z - mean, dx3 = v.w - mean;
    float q = dx0 * dx0 + dx1 * dx1 + dx2 * dx2 + dx3 * dx3;
    __syncthreads();
    #pragma unroll
    for (int off = 32; off > 0; off >>= 1) q += __shfl_down(q, off, 64);
    if (lane == 0) red[wave] = q;
    __syncthreads();
    const float var = (red[0] + red[1] + red[2] + red[3]) * (1.0f / DIMD);
    const float rstd = rsqrtf(var + 1e-5f);
    float4 g4 = ((const float4*)g)[threadIdx.x];
    float4 b4 = ((const float4*)beta)[threadIdx.x];
    float4 o;
    o.x = dx0 * rstd * g4.x + b4.x;
    o.y = dx1 * rstd * g4.y + b4.y;
    o.z = dx2 * rstd * g4.z + b4.z;
    o.w = dx3 * rstd * g4.w + b4.w;
    p[threadIdx.x] = o;
}

template <int MODE>
__global__ __launch_bounds__(256) void ff_gemm(const float* __restrict__ A,
                                               const float* __restrict__ W,
                                               const float* __restrict__ bias,
                                               const float* __restrict__ mask,
                                               float* __restrict__ out) {
    __shared__ float As[BM][BK + 1];
    __shared__ float Bs[BK][BN + 1];
    const int tid = threadIdx.x;
    const int tx = tid & 15;
    const int ty = tid >> 4;
    const int m0 = blockIdx.y * BM;
    const int n0 = blockIdx.x * BN;
    float acc[4][4] = {};
    for (int k0 = 0; k0 < DIMD; k0 += BK) {
        __syncthreads();
        for (int f = tid; f < BM * BK; f += 256) {
            int i = f / BK, k = f % BK;
            As[i][k] = A[(size_t)(m0 + i) * DIMD + k0 + k];
        }
        for (int f = tid; f < BK * BN; f += 256) {
            int k = f / BN, j = f % BN;
            Bs[k][j] = W[(size_t)(k0 + k) * DIMD + n0 + j];
        }
        __syncthreads();
        #pragma unroll
        for (int k = 0; k < BK; ++k) {
            float a[4], bv[4];
            #pragma unroll
            for (int i = 0; i < 4; ++i) a[i] = As[ty * 4 + i][k];
            #pragma unroll
            for (int j = 0; j < 4; ++j) bv[j] = Bs[k][tx * 4 + j];
            #pragma unroll
            for (int i = 0; i < 4; ++i)
                #pragma unroll
                for (int j = 0; j < 4; ++j) acc[i][j] += a[i] * bv[j];
        }
    }
    #pragma unroll
    for (int i = 0; i < 4; ++i) {
        int m = m0 + ty * 4 + i;
        float mk = (MODE == 1) ? mask[m] : 1.0f;
        #pragma unroll
        for (int j = 0; j < 4; ++j) {
            int n = n0 + tx * 4 + j;
            float v = acc[i][j] + bias[n];
            if (MODE == 0) v = 0.5f * v * (1.0f + erff(v * 0.70710678118654752f));
            else v *= mk;
            out[(size_t)m * DIMD + n] = v;
        }
    }
}

// ===========================================================================
extern "C" void kernel_launch(void* const* d_in, const int* in_sizes, int n_in,
                              void* d_out, int out_size, void* d_ws, size_t ws_size,
                              hipStream_t stream) {
    const float* x    = (const float*)d_in[0];
    const float* mask = (const float*)d_in[1];
    const float* ln_g = (const float*)d_in[2];
    const float* ln_b = (const float*)d_in[3];
    const float* w1   = (const float*)d_in[4];
    const float* b1   = (const float*)d_in[5];
    const float* w2   = (const float*)d_in[6];
    const float* b2   = (const float*)d_in[7];
    float* out = (float*)d_out;

    const size_t MB = 1024 * 1024;
    dim3 blk(256);

    if (ws_size >= 70 * MB) {
        char* w = (char*)d_ws;
        unsigned short* Acos = (unsigned short*)w;             // @0,  2.4 MB (dead after cos gemm)
        unsigned short* Xe   = (unsigned short*)(w + 4 * MB);  // @4,  17.8 MB (dead after cos gemm)
        unsigned short* y    = (unsigned short*)(w + 32 * MB); // @32, 32 MB (dead after ln)
        unsigned short* t    = (unsigned short*)w;             // @0,  32 MB (over Acos+Xe)
        unsigned short* h    = (unsigned short*)(w + 32 * MB); // @32, 32 MB (over y)
        unsigned short* W1t  = (unsigned short*)(w + 64 * MB); // 2 MB
        unsigned short* W2t  = (unsigned short*)(w + 66 * MB); // 2 MB

        build_acos<<<dim3(MF), blk, 0, stream>>>(Acos);
        build_xe<<<dim3(8192 / 64, KF / 32), blk, 0, stream>>>(x, Xe);
        pack_wt<<<dim3(1024 / 64, 1024 / 32), blk, 0, stream>>>(w1, W1t);
        pack_wt<<<dim3(1024 / 64, 1024 / 32), blk, 0, stream>>>(w2, W2t);

        // y[b,s,:] and y[b,2048-s,:] = bf16(x + 1024 * cos-transform)
        gemm_bt<0><<<dim3(8192 / 128, MF / 128), blk, 0, stream>>>(
            Acos, Xe, KF, KF, KF, 0, x, nullptr, nullptr, y);
        // t = bf16(LayerNorm(y))
        ln_bf<<<dim3(ROWS), blk, 0, stream>>>(y, ln_g, ln_b, t);
        // h = bf16(gelu(t @ W1 + b1))
        gemm_bt<1><<<dim3(1024 / 128, ROWS / 128), blk, 0, stream>>>(
            t, W1t, 1024, 1024, 1024, 1024, nullptr, b1, nullptr, h);
        // out = (h @ W2 + b2) * mask
        gemm_bt<2><<<dim3(1024 / 128, ROWS / 128), blk, 0, stream>>>(
            h, W2t, 1024, 1024, 1024, 1024, nullptr, b2, mask, out);
    } else {
        // fp32 fallback (round-1 path)
        float* yf = (float*)d_ws;
        const size_t bufBytes = (size_t)ROWS * DIMD * sizeof(float);
        fft_cos_kernel<<<dim3(DIMD / BN, SEQ / BM, BATCH), blk, 0, stream>>>(x, yf);
        ln_kernel<<<dim3(ROWS), blk, 0, stream>>>(yf, ln_g, ln_b);
        ff_gemm<0><<<dim3(DIMD / BN, ROWS / BM), blk, 0, stream>>>(yf, w1, b1, nullptr, out);
        ff_gemm<1><<<dim3(DIMD / BN, ROWS / BM), blk, 0, stream>>>(out, w2, b2, mask, yf);
        hipMemcpyAsync(d_out, yf, bufBytes, hipMemcpyDeviceToDevice, stream);
    }
}

// Round 5
// 348.496 us; speedup vs baseline: 1.0916x; 1.0916x over previous
//
#include <hip/hip_runtime.h>
#include <math.h>

#define DIMD 1024
#define SEQ  2048
#define BATCH 8
#define ROWS (BATCH * SEQ)   // 16384

#define MF 1152              // folded cos-GEMM M (rows s=0..1151, need 0..1024)
#define KF 1088              // folded cos-GEMM K (t=0..1024 + pad)

typedef __attribute__((ext_vector_type(8))) short bf16x8;
typedef __attribute__((ext_vector_type(4))) float f32x4;
typedef __attribute__((ext_vector_type(8))) unsigned short ushort8;

// ---------------- helpers ----------------
__device__ __forceinline__ unsigned short f2bf(float f) {
    unsigned u = __float_as_uint(f);
    unsigned r = (u + 0x7FFFu + ((u >> 16) & 1u)) >> 16;
    return (unsigned short)r;
}
__device__ __forceinline__ float bf2f(unsigned short h) {
    return __uint_as_float(((unsigned)h) << 16);
}
__device__ __forceinline__ void gl_lds16(const void* g, void* l) {
    __builtin_amdgcn_global_load_lds(
        (const __attribute__((address_space(1))) unsigned int*)g,
        (__attribute__((address_space(3))) unsigned int*)l, 16, 0, 0);
}

// ---------------------------------------------------------------------------
// Precompute kernels
// ---------------------------------------------------------------------------

// Acos[s][t] = bf16(1024*cos(pi*((s*t)&2047)/1024)) for t<=1024, else 0.
// The 1024 scale is a pure exponent shift -> exact in bf16.
__global__ __launch_bounds__(256) void build_acos(unsigned short* __restrict__ Acos) {
    int s = blockIdx.x;                       // 0..MF-1
    for (int t = threadIdx.x; t < KF; t += 256) {
        float c = 0.0f;
        if (t <= 1024) {
            int prod = (s * t) & (SEQ - 1);
            c = 1024.0f * cospif((float)prod * (1.0f / 1024.0f));
        }
        Acos[(size_t)s * KF + t] = f2bf(c);
    }
}

// Xe[n = b*1024+d][t] = bf16( x[b,t,rev(d)] + x[b,2048-t,rev(d)] ) (folded)
//   t=0: x[b,0,rd];  t=1024: x[b,1024,rd];  t>1024: 0.      8192 x KF
__global__ __launch_bounds__(256) void build_xe(const float* __restrict__ x,
                                                unsigned short* __restrict__ Xe) {
    int lane = threadIdx.x & 63;
    int oct  = threadIdx.x >> 6;
    int n = blockIdx.x * 64 + lane;           // 0..8191
    int b = n >> 10, d = n & 1023;
    int rd = (DIMD - d) & (DIMD - 1);
    int t0 = blockIdx.y * 32 + oct * 8;       // 0..KF-8
    const float* xb = x + (size_t)b * SEQ * DIMD + rd;
    ushort8 tmp;
    #pragma unroll
    for (int j = 0; j < 8; ++j) {
        int t = t0 + j;
        float v;
        if (t == 0)          v = xb[0];
        else if (t < 1024)   v = xb[(size_t)t * DIMD] + xb[(size_t)(2048 - t) * DIMD];
        else if (t == 1024)  v = xb[(size_t)1024 * DIMD];
        else                 v = 0.0f;
        tmp[j] = f2bf(v);
    }
    *(ushort8*)&Xe[(size_t)n * KF + t0] = tmp;
}

// Wt[n][k] = bf16(W[k][n]),  1024 x 1024
__global__ __launch_bounds__(256) void pack_wt(const float* __restrict__ W,
                                               unsigned short* __restrict__ Wt) {
    int lane = threadIdx.x & 63;
    int oct = threadIdx.x >> 6;
    int n = blockIdx.x * 64 + lane;
    int k0 = blockIdx.y * 32 + oct * 8;
    ushort8 tmp;
    #pragma unroll
    for (int j = 0; j < 8; ++j) tmp[j] = f2bf(W[(size_t)(k0 + j) * DIMD + n]);
    *(ushort8*)&Wt[(size_t)n * DIMD + k0] = tmp;
}

// ---------------------------------------------------------------------------
// MFMA GEMM: C[M x N] = A[M x K] @ B^T[N x K]   (bf16 in, fp32 acc)
// 128x128 tile, BK=64, 256 threads = 4 waves (2x2 of 64x64 each)
// MODE 0 (cos): F_f32[row*ldc+col] = acc                (natural grid)
// MODE 1 (ff1): h_bf16[row*ldc+col] = bf16(gelu(acc + bias[col]))  [XCD swizzle]
// MODE 2 (ff2): out_f32[row*ldc+col] = (acc + bias[col]) * mask[row] [XCD swizzle]
// ---------------------------------------------------------------------------
template <int MODE>
__global__ __launch_bounds__(256) void gemm_bt(const unsigned short* __restrict__ A,
                                               const unsigned short* __restrict__ B,
                                               int K, int lda, int ldb, int ldc,
                                               const float* __restrict__ bias,
                                               const float* __restrict__ mask,
                                               void* __restrict__ outp) {
    __shared__ unsigned short As[128 * 64];
    __shared__ unsigned short Bs[128 * 64];

    const int tid = threadIdx.x;
    const int lane = tid & 63;
    const int wv = tid >> 6;
    const int wm = wv & 1;
    const int wn = wv >> 1;
    const int fr = lane & 15;
    const int quad = lane >> 4;

    int bx = blockIdx.x, by = blockIdx.y;
    if (MODE != 0) {
        // XCD-aware swizzle: grid is (8, 128); linear = bx + 8*by; XCD ~ lin&7.
        // Give XCD c the m-tiles {8g+c} so its L2 re-uses each A-tile across
        // all 8 n-tiles (L2 working set 6 MB instead of 32 MB).
        // [R3->R4 evidence: FF gemm FETCH_SIZE 133 MB -> 60 MB]
        int lin = bx + 8 * by;
        int c = lin & 7;
        int g = lin >> 3;          // 0..127
        bx = g & 7;                // n-tile
        by = (g >> 3) * 8 + c;     // m-tile
    }
    const int m0 = by * 128;
    const int n0 = bx * 128;

    const int st_row = (lane >> 3);          // 0..7 within chunk
    const int st_col = (lane & 7) * 8;       // element offset within row

    f32x4 acc[4][4] = {};

    for (int k0 = 0; k0 < K; k0 += 64) {
        __syncthreads();
        #pragma unroll
        for (int i = 0; i < 4; ++i) {
            int chunk = wv * 4 + i;          // 0..15
            int ar = m0 + chunk * 8 + st_row;
            int br = n0 + chunk * 8 + st_row;
            gl_lds16(&A[(size_t)ar * lda + k0 + st_col], &As[chunk * 512]);
            gl_lds16(&B[(size_t)br * ldb + k0 + st_col], &Bs[chunk * 512]);
        }
        __syncthreads();

        #pragma unroll
        for (int ks = 0; ks < 2; ++ks) {
            bf16x8 af[4], bfv[4];
            #pragma unroll
            for (int i = 0; i < 4; ++i)
                af[i] = *(const bf16x8*)&As[(wm * 64 + i * 16 + fr) * 64 + ks * 32 + quad * 8];
            #pragma unroll
            for (int j = 0; j < 4; ++j)
                bfv[j] = *(const bf16x8*)&Bs[(wn * 64 + j * 16 + fr) * 64 + ks * 32 + quad * 8];
            #pragma unroll
            for (int i = 0; i < 4; ++i)
                #pragma unroll
                for (int j = 0; j < 4; ++j)
                    acc[i][j] = __builtin_amdgcn_mfma_f32_16x16x32_bf16(af[i], bfv[j], acc[i][j], 0, 0, 0);
        }
    }

    // epilogue: row = m0 + wm*64 + i*16 + quad*4 + r ; col = n0 + wn*64 + j*16 + fr
    #pragma unroll
    for (int i = 0; i < 4; ++i) {
        int rowb = m0 + wm * 64 + i * 16 + quad * 4;
        #pragma unroll
        for (int j = 0; j < 4; ++j) {
            int col = n0 + wn * 64 + j * 16 + fr;
            #pragma unroll
            for (int r = 0; r < 4; ++r) {
                float v = acc[i][j][r];
                int row = rowb + r;
                if (MODE == 0) {
                    ((float*)outp)[(size_t)row * ldc + col] = v;
                } else if (MODE == 1) {
                    v += bias[col];
                    v = 0.5f * v * (1.0f + erff(v * 0.70710678118654752f));
                    ((unsigned short*)outp)[(size_t)row * ldc + col] = f2bf(v);
                } else {
                    v += bias[col];
                    v *= mask[row];
                    ((float*)outp)[(size_t)row * ldc + col] = v;
                }
            }
        }
    }
}

// ---------------------------------------------------------------------------
// LayerNorm pair: block (sp, b) reads F[sp] ONCE, handles rows s=sp and
// s=2048-sp.  y = x[b,s,:] + F[sp][b*1024+:]  (scale already in Acos).
// Writes bf16 t.
// ---------------------------------------------------------------------------
__global__ __launch_bounds__(256) void ln_pair(const float* __restrict__ x,
                                               const float* __restrict__ F,
                                               const float* __restrict__ g,
                                               const float* __restrict__ beta,
                                               unsigned short* __restrict__ t) {
    const int sp = blockIdx.x;                // 0..1024
    const int b  = blockIdx.y;

    float4 fv = ((const float4*)(F + (size_t)sp * 8192 + (size_t)b * 1024))[threadIdx.x];
    float4 g4 = ((const float4*)g)[threadIdx.x];
    float4 b4 = ((const float4*)beta)[threadIdx.x];

    __shared__ float red[4];
    const int wave = threadIdx.x >> 6;
    const int lane = threadIdx.x & 63;

    const int nrows = (sp >= 1 && sp <= 1023) ? 2 : 1;
    for (int p = 0; p < nrows; ++p) {
        int s = p ? (2048 - sp) : sp;
        int row = b * SEQ + s;
        float4 xv = ((const float4*)(x + (size_t)row * DIMD))[threadIdx.x];
        float v0 = xv.x + fv.x, v1 = xv.y + fv.y, v2 = xv.z + fv.z, v3 = xv.w + fv.w;

        float sm = v0 + v1 + v2 + v3;
        #pragma unroll
        for (int off = 32; off > 0; off >>= 1) sm += __shfl_down(sm, off, 64);
        if (lane == 0) red[wave] = sm;
        __syncthreads();
        const float mean = (red[0] + red[1] + red[2] + red[3]) * (1.0f / DIMD);

        float dx0 = v0 - mean, dx1 = v1 - mean, dx2 = v2 - mean, dx3 = v3 - mean;
        float q = dx0 * dx0 + dx1 * dx1 + dx2 * dx2 + dx3 * dx3;
        __syncthreads();
        #pragma unroll
        for (int off = 32; off > 0; off >>= 1) q += __shfl_down(q, off, 64);
        if (lane == 0) red[wave] = q;
        __syncthreads();
        const float var = (red[0] + red[1] + red[2] + red[3]) * (1.0f / DIMD);
        const float rstd = rsqrtf(var + 1e-5f);

        ushort4 o;
        o.x = f2bf(dx0 * rstd * g4.x + b4.x);
        o.y = f2bf(dx1 * rstd * g4.y + b4.y);
        o.z = f2bf(dx2 * rstd * g4.z + b4.z);
        o.w = f2bf(dx3 * rstd * g4.w + b4.w);
        ((ushort4*)(t + (size_t)row * DIMD))[threadIdx.x] = o;
        __syncthreads();
    }
}

// ===========================================================================
// Fallback fp32 path (round-1 kernels) for small workspace
// ===========================================================================
#define BM 64
#define BN 64
#define BK 16

__global__ __launch_bounds__(256) void fft_cos_kernel(const float* __restrict__ x,
                                                      float* __restrict__ y) {
    __shared__ float tab[SEQ];
    __shared__ float As[BM][BK + 1];
    __shared__ float Bs[BK][BN + 1];
    const int tid = threadIdx.x;
    const int b = blockIdx.z;
    const int s0 = blockIdx.y * BM;
    const int n0 = blockIdx.x * BN;
    for (int i = tid; i < SEQ; i += 256) tab[i] = cospif((float)i * (1.0f / 1024.0f));
    const int tx = tid & 15;
    const int ty = tid >> 4;
    float acc[4][4] = {};
    const float* Xb = x + (size_t)b * SEQ * DIMD;
    for (int k0 = 0; k0 < SEQ; k0 += BK) {
        __syncthreads();
        for (int f = tid; f < BM * BK; f += 256) {
            int i = f / BK, k = f % BK;
            int prod = (s0 + i) * (k0 + k);
            As[i][k] = tab[prod & (SEQ - 1)];
        }
        for (int f = tid; f < BK * BN; f += 256) {
            int k = f / BN, j = f % BN;
            int d = n0 + j;
            int rd = (DIMD - d) & (DIMD - 1);
            Bs[k][j] = Xb[(size_t)(k0 + k) * DIMD + rd];
        }
        __syncthreads();
        #pragma unroll
        for (int k = 0; k < BK; ++k) {
            float a[4], bv[4];
            #pragma unroll
            for (int i = 0; i < 4; ++i) a[i] = As[ty * 4 + i][k];
            #pragma unroll
            for (int j = 0; j < 4; ++j) bv[j] = Bs[k][tx * 4 + j];
            #pragma unroll
            for (int i = 0; i < 4; ++i)
                #pragma unroll
                for (int j = 0; j < 4; ++j) acc[i][j] += a[i] * bv[j];
        }
    }
    #pragma unroll
    for (int i = 0; i < 4; ++i) {
        int s = s0 + ty * 4 + i;
        #pragma unroll
        for (int j = 0; j < 4; ++j) {
            int d = n0 + tx * 4 + j;
            y[((size_t)b * SEQ + s) * DIMD + d] = Xb[(size_t)s * DIMD + d] + 1024.0f * acc[i][j];
        }
    }
}

__global__ __launch_bounds__(256) void ln_kernel(float* __restrict__ y,
                                                 const float* __restrict__ g,
                                                 const float* __restrict__ beta) {
    const int row = blockIdx.x;
    float4* p = (float4*)(y + (size_t)row * DIMD);
    float4 v = p[threadIdx.x];
    __shared__ float red[4];
    const int wave = threadIdx.x >> 6;
    const int lane = threadIdx.x & 63;
    float s = v.x + v.y + v.z + v.w;
    #pragma unroll
    for (int off = 32; off > 0; off >>= 1) s += __shfl_down(s, off, 64);
    if (lane == 0) red[wave] = s;
    __syncthreads();
    const float mean = (red[0] + red[1] + red[2] + red[3]) * (1.0f / DIMD);
    float dx0 = v.x - mean, dx1 = v.y - mean, dx2 = v.z - mean, dx3 = v.w - mean;
    float q = dx0 * dx0 + dx1 * dx1 + dx2 * dx2 + dx3 * dx3;
    __syncthreads();
    #pragma unroll
    for (int off = 32; off > 0; off >>= 1) q += __shfl_down(q, off, 64);
    if (lane == 0) red[wave] = q;
    __syncthreads();
    const float var = (red[0] + red[1] + red[2] + red[3]) * (1.0f / DIMD);
    const float rstd = rsqrtf(var + 1e-5f);
    float4 g4 = ((const float4*)g)[threadIdx.x];
    float4 b4 = ((const float4*)beta)[threadIdx.x];
    float4 o;
    o.x = dx0 * rstd * g4.x + b4.x;
    o.y = dx1 * rstd * g4.y + b4.y;
    o.z = dx2 * rstd * g4.z + b4.z;
    o.w = dx3 * rstd * g4.w + b4.w;
    p[threadIdx.x] = o;
}

template <int MODE>
__global__ __launch_bounds__(256) void ff_gemm(const float* __restrict__ A,
                                               const float* __restrict__ W,
                                               const float* __restrict__ bias,
                                               const float* __restrict__ mask,
                                               float* __restrict__ out) {
    __shared__ float As[BM][BK + 1];
    __shared__ float Bs[BK][BN + 1];
    const int tid = threadIdx.x;
    const int tx = tid & 15;
    const int ty = tid >> 4;
    const int m0 = blockIdx.y * BM;
    const int n0 = blockIdx.x * BN;
    float acc[4][4] = {};
    for (int k0 = 0; k0 < DIMD; k0 += BK) {
        __syncthreads();
        for (int f = tid; f < BM * BK; f += 256) {
            int i = f / BK, k = f % BK;
            As[i][k] = A[(size_t)(m0 + i) * DIMD + k0 + k];
        }
        for (int f = tid; f < BK * BN; f += 256) {
            int k = f / BN, j = f % BN;
            Bs[k][j] = W[(size_t)(k0 + k) * DIMD + n0 + j];
        }
        __syncthreads();
        #pragma unroll
        for (int k = 0; k < BK; ++k) {
            float a[4], bv[4];
            #pragma unroll
            for (int i = 0; i < 4; ++i) a[i] = As[ty * 4 + i][k];
            #pragma unroll
            for (int j = 0; j < 4; ++j) bv[j] = Bs[k][tx * 4 + j];
            #pragma unroll
            for (int i = 0; i < 4; ++i)
                #pragma unroll
                for (int j = 0; j < 4; ++j) acc[i][j] += a[i] * bv[j];
        }
    }
    #pragma unroll
    for (int i = 0; i < 4; ++i) {
        int m = m0 + ty * 4 + i;
        float mk = (MODE == 1) ? mask[m] : 1.0f;
        #pragma unroll
        for (int j = 0; j < 4; ++j) {
            int n = n0 + tx * 4 + j;
            float v = acc[i][j] + bias[n];
            if (MODE == 0) v = 0.5f * v * (1.0f + erff(v * 0.70710678118654752f));
            else v *= mk;
            out[(size_t)m * DIMD + n] = v;
        }
    }
}

// ===========================================================================
extern "C" void kernel_launch(void* const* d_in, const int* in_sizes, int n_in,
                              void* d_out, int out_size, void* d_ws, size_t ws_size,
                              hipStream_t stream) {
    const float* x    = (const float*)d_in[0];
    const float* mask = (const float*)d_in[1];
    const float* ln_g = (const float*)d_in[2];
    const float* ln_b = (const float*)d_in[3];
    const float* w1   = (const float*)d_in[4];
    const float* b1   = (const float*)d_in[5];
    const float* w2   = (const float*)d_in[6];
    const float* b2   = (const float*)d_in[7];
    float* out = (float*)d_out;

    const size_t MB = 1024 * 1024;
    dim3 blk(256);

    if (ws_size >= 70 * MB) {
        char* w = (char*)d_ws;
        unsigned short* Acos = (unsigned short*)w;             // @0,  2.4 MB (dead after cos gemm)
        unsigned short* Xe   = (unsigned short*)(w + 4 * MB);  // @4,  17.8 MB (dead after cos gemm)
        unsigned short* t    = (unsigned short*)(w + 32 * MB); // @32, 32 MB
        unsigned short* h    = (unsigned short*)w;             // @0,  32 MB (over Acos+Xe after ln)
        unsigned short* W1t  = (unsigned short*)(w + 64 * MB); // 2 MB
        unsigned short* W2t  = (unsigned short*)(w + 66 * MB); // 2 MB
        float* F = (float*)d_out;                              // 37.75 MB scratch in d_out

        build_acos<<<dim3(MF), blk, 0, stream>>>(Acos);
        build_xe<<<dim3(8192 / 64, KF / 32), blk, 0, stream>>>(x, Xe);
        pack_wt<<<dim3(1024 / 64, 1024 / 32), blk, 0, stream>>>(w1, W1t);
        pack_wt<<<dim3(1024 / 64, 1024 / 32), blk, 0, stream>>>(w2, W2t);

        // F[s][n] = sum_t Acos[s][t] * Xe[n][t]   (scale folded into Acos)
        gemm_bt<0><<<dim3(8192 / 128, MF / 128), blk, 0, stream>>>(
            Acos, Xe, KF, KF, KF, 8192, nullptr, nullptr, F);
        // t = bf16(LayerNorm(x + F[mirror]))  — one F-row read per pair
        ln_pair<<<dim3(1025, BATCH), blk, 0, stream>>>(x, F, ln_g, ln_b, t);
        // h = bf16(gelu(t @ W1 + b1))
        gemm_bt<1><<<dim3(1024 / 128, ROWS / 128), blk, 0, stream>>>(
            t, W1t, 1024, 1024, 1024, 1024, b1, nullptr, h);
        // out = (h @ W2 + b2) * mask
        gemm_bt<2><<<dim3(1024 / 128, ROWS / 128), blk, 0, stream>>>(
            h, W2t, 1024, 1024, 1024, 1024, b2, mask, out);
    } else {
        // fp32 fallback (round-1 path)
        float* yf = (float*)d_ws;
        const size_t bufBytes = (size_t)ROWS * DIMD * sizeof(float);
        fft_cos_kernel<<<dim3(DIMD / BN, SEQ / BM, BATCH), blk, 0, stream>>>(x, yf);
        ln_kernel<<<dim3(ROWS), blk, 0, stream>>>(yf, ln_g, ln_b);
        ff_gemm<0><<<dim3(DIMD / BN, ROWS / BM), blk, 0, stream>>>(yf, w1, b1, nullptr, out);
        ff_gemm<1><<<dim3(DIMD / BN, ROWS / BM), blk, 0, stream>>>(out, w2, b2, mask, yf);
        hipMemcpyAsync(d_out, yf, bufBytes, hipMemcpyDeviceToDevice, stream);
    }
}

// Round 6
// 327.095 us; speedup vs baseline: 1.1630x; 1.0654x over previous
//
#include <hip/hip_runtime.h>
#include <math.h>

#define DIMD 1024
#define SEQ  2048
#define BATCH 8
#define ROWS (BATCH * SEQ)   // 16384

#define MF 1152              // folded cos-GEMM M (rows s=0..1151, need 0..1024)
#define KF 1088              // folded cos-GEMM K (t=0..1024 + pad)

typedef __attribute__((ext_vector_type(8))) short bf16x8;
typedef __attribute__((ext_vector_type(4))) float f32x4;
typedef __attribute__((ext_vector_type(8))) unsigned short ushort8;

// ---------------- helpers ----------------
__device__ __forceinline__ unsigned short f2bf(float f) {
    unsigned u = __float_as_uint(f);
    unsigned r = (u + 0x7FFFu + ((u >> 16) & 1u)) >> 16;
    return (unsigned short)r;
}
__device__ __forceinline__ float bf2f(unsigned short h) {
    return __uint_as_float(((unsigned)h) << 16);
}
__device__ __forceinline__ void gl_lds16(const void* g, void* l) {
    __builtin_amdgcn_global_load_lds(
        (const __attribute__((address_space(1))) unsigned int*)g,
        (__attribute__((address_space(3))) unsigned int*)l, 16, 0, 0);
}

// ---------------------------------------------------------------------------
// Precompute kernels
// ---------------------------------------------------------------------------

// Acos[s][t] = bf16(1024*cos(pi*((s*t)&2047)/1024)) for t<=1024, else 0.
// The 1024 scale is a pure exponent shift -> exact in bf16.
__global__ __launch_bounds__(256) void build_acos(unsigned short* __restrict__ Acos) {
    int s = blockIdx.x;                       // 0..MF-1
    for (int t = threadIdx.x; t < KF; t += 256) {
        float c = 0.0f;
        if (t <= 1024) {
            int prod = (s * t) & (SEQ - 1);
            c = 1024.0f * cospif((float)prod * (1.0f / 1024.0f));
        }
        Acos[(size_t)s * KF + t] = f2bf(c);
    }
}

// Xe[n = b*1024+d][t] = bf16( x[b,t,rev(d)] + x[b,2048-t,rev(d)] ) (folded)
//   t=0: x[b,0,rd];  t=1024: x[b,1024,rd];  t>1024: 0.      8192 x KF
__global__ __launch_bounds__(256) void build_xe(const float* __restrict__ x,
                                                unsigned short* __restrict__ Xe) {
    int lane = threadIdx.x & 63;
    int oct  = threadIdx.x >> 6;
    int n = blockIdx.x * 64 + lane;           // 0..8191
    int b = n >> 10, d = n & 1023;
    int rd = (DIMD - d) & (DIMD - 1);
    int t0 = blockIdx.y * 32 + oct * 8;       // 0..KF-8
    const float* xb = x + (size_t)b * SEQ * DIMD + rd;
    ushort8 tmp;
    #pragma unroll
    for (int j = 0; j < 8; ++j) {
        int t = t0 + j;
        float v;
        if (t == 0)          v = xb[0];
        else if (t < 1024)   v = xb[(size_t)t * DIMD] + xb[(size_t)(2048 - t) * DIMD];
        else if (t == 1024)  v = xb[(size_t)1024 * DIMD];
        else                 v = 0.0f;
        tmp[j] = f2bf(v);
    }
    *(ushort8*)&Xe[(size_t)n * KF + t0] = tmp;
}

// Wt[n][k] = bf16(W[k][n]),  1024 x 1024
__global__ __launch_bounds__(256) void pack_wt(const float* __restrict__ W,
                                               unsigned short* __restrict__ Wt) {
    int lane = threadIdx.x & 63;
    int oct = threadIdx.x >> 6;
    int n = blockIdx.x * 64 + lane;
    int k0 = blockIdx.y * 32 + oct * 8;
    ushort8 tmp;
    #pragma unroll
    for (int j = 0; j < 8; ++j) tmp[j] = f2bf(W[(size_t)(k0 + j) * DIMD + n]);
    *(ushort8*)&Wt[(size_t)n * DIMD + k0] = tmp;
}

// ---------------------------------------------------------------------------
// MFMA GEMM: C[M x N] = A[M x K] @ B^T[N x K]   (bf16 in, fp32 acc)
// 128x128 tile, BK=64, 256 threads = 4 waves (2x2 of 64x64 each)
// LDS layout is XOR-swizzled (16B-slot s of row r holds source col s^(r&7))
// to kill the 16-way bank-group conflict of the naive layout.
// [R5 evidence: SQ_LDS_BANK_CONFLICT 1.26e7 = 27% of kernel cycles]
// MODE 0 (cos): F_f32[row*ldc+col] = acc                (natural grid)
// MODE 1 (ff1): h_bf16[row*ldc+col] = bf16(gelu(acc + bias[col]))  [XCD swizzle]
// MODE 2 (ff2): out_f32[row*ldc+col] = (acc + bias[col]) * mask[row] [XCD swizzle]
// ---------------------------------------------------------------------------
template <int MODE>
__global__ __launch_bounds__(256) void gemm_bt(const unsigned short* __restrict__ A,
                                               const unsigned short* __restrict__ B,
                                               int K, int lda, int ldb, int ldc,
                                               const float* __restrict__ bias,
                                               const float* __restrict__ mask,
                                               void* __restrict__ outp) {
    __shared__ unsigned short As[128 * 64];
    __shared__ unsigned short Bs[128 * 64];

    const int tid = threadIdx.x;
    const int lane = tid & 63;
    const int wv = tid >> 6;
    const int wm = wv & 1;
    const int wn = wv >> 1;
    const int fr = lane & 15;
    const int quad = lane >> 4;

    int bx = blockIdx.x, by = blockIdx.y;
    if (MODE != 0) {
        // XCD-aware swizzle: grid is (8, 128); linear = bx + 8*by; XCD ~ lin&7.
        // Give XCD c the m-tiles {8g+c} so its L2 re-uses each A-tile across
        // all 8 n-tiles (L2 working set 6 MB instead of 32 MB).
        // [R3->R4 evidence: FF gemm FETCH_SIZE 133 MB -> 60 MB -> 33 MB ideal]
        int lin = bx + 8 * by;
        int c = lin & 7;
        int g = lin >> 3;          // 0..127
        bx = g & 7;                // n-tile
        by = (g >> 3) * 8 + c;     // m-tile
    }
    const int m0 = by * 128;
    const int n0 = bx * 128;

    // staging: chunk = 8 rows x 64 cols; lane -> (st_row, 16B-slot lane&7).
    // XOR-swizzle: lane fetches source 16B-col (lane&7)^st_row, so LDS slot s
    // of row r holds source col s^(r&7).
    const int st_row = (lane >> 3);              // 0..7 within chunk
    const int st_col = ((lane & 7) ^ st_row) * 8; // swizzled source element col

    f32x4 acc[4][4] = {};

    for (int k0 = 0; k0 < K; k0 += 64) {
        __syncthreads();
        #pragma unroll
        for (int i = 0; i < 4; ++i) {
            int chunk = wv * 4 + i;          // 0..15
            int ar = m0 + chunk * 8 + st_row;
            int br = n0 + chunk * 8 + st_row;
            gl_lds16(&A[(size_t)ar * lda + k0 + st_col], &As[chunk * 512]);
            gl_lds16(&B[(size_t)br * ldb + k0 + st_col], &Bs[chunk * 512]);
        }
        __syncthreads();

        const int sw = fr & 7;               // row-low bits for de-swizzle
        #pragma unroll
        for (int ks = 0; ks < 2; ++ks) {
            const int slot = (ks * 4 + quad) ^ sw;   // de-swizzled 16B slot
            bf16x8 af[4], bfv[4];
            #pragma unroll
            for (int i = 0; i < 4; ++i)
                af[i] = *(const bf16x8*)&As[(wm * 64 + i * 16 + fr) * 64 + slot * 8];
            #pragma unroll
            for (int j = 0; j < 4; ++j)
                bfv[j] = *(const bf16x8*)&Bs[(wn * 64 + j * 16 + fr) * 64 + slot * 8];
            #pragma unroll
            for (int i = 0; i < 4; ++i)
                #pragma unroll
                for (int j = 0; j < 4; ++j)
                    acc[i][j] = __builtin_amdgcn_mfma_f32_16x16x32_bf16(af[i], bfv[j], acc[i][j], 0, 0, 0);
        }
    }

    // epilogue: row = m0 + wm*64 + i*16 + quad*4 + r ; col = n0 + wn*64 + j*16 + fr
    #pragma unroll
    for (int i = 0; i < 4; ++i) {
        int rowb = m0 + wm * 64 + i * 16 + quad * 4;
        #pragma unroll
        for (int j = 0; j < 4; ++j) {
            int col = n0 + wn * 64 + j * 16 + fr;
            #pragma unroll
            for (int r = 0; r < 4; ++r) {
                float v = acc[i][j][r];
                int row = rowb + r;
                if (MODE == 0) {
                    ((float*)outp)[(size_t)row * ldc + col] = v;
                } else if (MODE == 1) {
                    v += bias[col];
                    v = 0.5f * v * (1.0f + erff(v * 0.70710678118654752f));
                    ((unsigned short*)outp)[(size_t)row * ldc + col] = f2bf(v);
                } else {
                    v += bias[col];
                    v *= mask[row];
                    ((float*)outp)[(size_t)row * ldc + col] = v;
                }
            }
        }
    }
}

// ---------------------------------------------------------------------------
// LayerNorm pair: block (sp, b) reads F[sp] ONCE, handles rows s=sp and
// s=2048-sp.  y = x[b,s,:] + F[sp][b*1024+:]  (scale already in Acos).
// Writes bf16 t.
// ---------------------------------------------------------------------------
__global__ __launch_bounds__(256) void ln_pair(const float* __restrict__ x,
                                               const float* __restrict__ F,
                                               const float* __restrict__ g,
                                               const float* __restrict__ beta,
                                               unsigned short* __restrict__ t) {
    const int sp = blockIdx.x;                // 0..1024
    const int b  = blockIdx.y;

    float4 fv = ((const float4*)(F + (size_t)sp * 8192 + (size_t)b * 1024))[threadIdx.x];
    float4 g4 = ((const float4*)g)[threadIdx.x];
    float4 b4 = ((const float4*)beta)[threadIdx.x];

    __shared__ float red[4];
    const int wave = threadIdx.x >> 6;
    const int lane = threadIdx.x & 63;

    const int nrows = (sp >= 1 && sp <= 1023) ? 2 : 1;
    for (int p = 0; p < nrows; ++p) {
        int s = p ? (2048 - sp) : sp;
        int row = b * SEQ + s;
        float4 xv = ((const float4*)(x + (size_t)row * DIMD))[threadIdx.x];
        float v0 = xv.x + fv.x, v1 = xv.y + fv.y, v2 = xv.z + fv.z, v3 = xv.w + fv.w;

        float sm = v0 + v1 + v2 + v3;
        #pragma unroll
        for (int off = 32; off > 0; off >>= 1) sm += __shfl_down(sm, off, 64);
        if (lane == 0) red[wave] = sm;
        __syncthreads();
        const float mean = (red[0] + red[1] + red[2] + red[3]) * (1.0f / DIMD);

        float dx0 = v0 - mean, dx1 = v1 - mean, dx2 = v2 - mean, dx3 = v3 - mean;
        float q = dx0 * dx0 + dx1 * dx1 + dx2 * dx2 + dx3 * dx3;
        __syncthreads();
        #pragma unroll
        for (int off = 32; off > 0; off >>= 1) q += __shfl_down(q, off, 64);
        if (lane == 0) red[wave] = q;
        __syncthreads();
        const float var = (red[0] + red[1] + red[2] + red[3]) * (1.0f / DIMD);
        const float rstd = rsqrtf(var + 1e-5f);

        ushort4 o;
        o.x = f2bf(dx0 * rstd * g4.x + b4.x);
        o.y = f2bf(dx1 * rstd * g4.y + b4.y);
        o.z = f2bf(dx2 * rstd * g4.z + b4.z);
        o.w = f2bf(dx3 * rstd * g4.w + b4.w);
        ((ushort4*)(t + (size_t)row * DIMD))[threadIdx.x] = o;
        __syncthreads();
    }
}

// ===========================================================================
// Fallback fp32 path (round-1 kernels) for small workspace
// ===========================================================================
#define BM 64
#define BN 64
#define BK 16

__global__ __launch_bounds__(256) void fft_cos_kernel(const float* __restrict__ x,
                                                      float* __restrict__ y) {
    __shared__ float tab[SEQ];
    __shared__ float As[BM][BK + 1];
    __shared__ float Bs[BK][BN + 1];
    const int tid = threadIdx.x;
    const int b = blockIdx.z;
    const int s0 = blockIdx.y * BM;
    const int n0 = blockIdx.x * BN;
    for (int i = tid; i < SEQ; i += 256) tab[i] = cospif((float)i * (1.0f / 1024.0f));
    const int tx = tid & 15;
    const int ty = tid >> 4;
    float acc[4][4] = {};
    const float* Xb = x + (size_t)b * SEQ * DIMD;
    for (int k0 = 0; k0 < SEQ; k0 += BK) {
        __syncthreads();
        for (int f = tid; f < BM * BK; f += 256) {
            int i = f / BK, k = f % BK;
            int prod = (s0 + i) * (k0 + k);
            As[i][k] = tab[prod & (SEQ - 1)];
        }
        for (int f = tid; f < BK * BN; f += 256) {
            int k = f / BN, j = f % BN;
            int d = n0 + j;
            int rd = (DIMD - d) & (DIMD - 1);
            Bs[k][j] = Xb[(size_t)(k0 + k) * DIMD + rd];
        }
        __syncthreads();
        #pragma unroll
        for (int k = 0; k < BK; ++k) {
            float a[4], bv[4];
            #pragma unroll
            for (int i = 0; i < 4; ++i) a[i] = As[ty * 4 + i][k];
            #pragma unroll
            for (int j = 0; j < 4; ++j) bv[j] = Bs[k][tx * 4 + j];
            #pragma unroll
            for (int i = 0; i < 4; ++i)
                #pragma unroll
                for (int j = 0; j < 4; ++j) acc[i][j] += a[i] * bv[j];
        }
    }
    #pragma unroll
    for (int i = 0; i < 4; ++i) {
        int s = s0 + ty * 4 + i;
        #pragma unroll
        for (int j = 0; j < 4; ++j) {
            int d = n0 + tx * 4 + j;
            y[((size_t)b * SEQ + s) * DIMD + d] = Xb[(size_t)s * DIMD + d] + 1024.0f * acc[i][j];
        }
    }
}

__global__ __launch_bounds__(256) void ln_kernel(float* __restrict__ y,
                                                 const float* __restrict__ g,
                                                 const float* __restrict__ beta) {
    const int row = blockIdx.x;
    float4* p = (float4*)(y + (size_t)row * DIMD);
    float4 v = p[threadIdx.x];
    __shared__ float red[4];
    const int wave = threadIdx.x >> 6;
    const int lane = threadIdx.x & 63;
    float s = v.x + v.y + v.z + v.w;
    #pragma unroll
    for (int off = 32; off > 0; off >>= 1) s += __shfl_down(s, off, 64);
    if (lane == 0) red[wave] = s;
    __syncthreads();
    const float mean = (red[0] + red[1] + red[2] + red[3]) * (1.0f / DIMD);
    float dx0 = v.x - mean, dx1 = v.y - mean, dx2 = v.z - mean, dx3 = v.w - mean;
    float q = dx0 * dx0 + dx1 * dx1 + dx2 * dx2 + dx3 * dx3;
    __syncthreads();
    #pragma unroll
    for (int off = 32; off > 0; off >>= 1) q += __shfl_down(q, off, 64);
    if (lane == 0) red[wave] = q;
    __syncthreads();
    const float var = (red[0] + red[1] + red[2] + red[3]) * (1.0f / DIMD);
    const float rstd = rsqrtf(var + 1e-5f);
    float4 g4 = ((const float4*)g)[threadIdx.x];
    float4 b4 = ((const float4*)beta)[threadIdx.x];
    float4 o;
    o.x = dx0 * rstd * g4.x + b4.x;
    o.y = dx1 * rstd * g4.y + b4.y;
    o.z = dx2 * rstd * g4.z + b4.z;
    o.w = dx3 * rstd * g4.w + b4.w;
    p[threadIdx.x] = o;
}

template <int MODE>
__global__ __launch_bounds__(256) void ff_gemm(const float* __restrict__ A,
                                               const float* __restrict__ W,
                                               const float* __restrict__ bias,
                                               const float* __restrict__ mask,
                                               float* __restrict__ out) {
    __shared__ float As[BM][BK + 1];
    __shared__ float Bs[BK][BN + 1];
    const int tid = threadIdx.x;
    const int tx = tid & 15;
    const int ty = tid >> 4;
    const int m0 = blockIdx.y * BM;
    const int n0 = blockIdx.x * BN;
    float acc[4][4] = {};
    for (int k0 = 0; k0 < DIMD; k0 += BK) {
        __syncthreads();
        for (int f = tid; f < BM * BK; f += 256) {
            int i = f / BK, k = f % BK;
            As[i][k] = A[(size_t)(m0 + i) * DIMD + k0 + k];
        }
        for (int f = tid; f < BK * BN; f += 256) {
            int k = f / BN, j = f % BN;
            Bs[k][j] = W[(size_t)(k0 + k) * DIMD + n0 + j];
        }
        __syncthreads();
        #pragma unroll
        for (int k = 0; k < BK; ++k) {
            float a[4], bv[4];
            #pragma unroll
            for (int i = 0; i < 4; ++i) a[i] = As[ty * 4 + i][k];
            #pragma unroll
            for (int j = 0; j < 4; ++j) bv[j] = Bs[k][tx * 4 + j];
            #pragma unroll
            for (int i = 0; i < 4; ++i)
                #pragma unroll
                for (int j = 0; j < 4; ++j) acc[i][j] += a[i] * bv[j];
        }
    }
    #pragma unroll
    for (int i = 0; i < 4; ++i) {
        int m = m0 + ty * 4 + i;
        float mk = (MODE == 1) ? mask[m] : 1.0f;
        #pragma unroll
        for (int j = 0; j < 4; ++j) {
            int n = n0 + tx * 4 + j;
            float v = acc[i][j] + bias[n];
            if (MODE == 0) v = 0.5f * v * (1.0f + erff(v * 0.70710678118654752f));
            else v *= mk;
            out[(size_t)m * DIMD + n] = v;
        }
    }
}

// ===========================================================================
extern "C" void kernel_launch(void* const* d_in, const int* in_sizes, int n_in,
                              void* d_out, int out_size, void* d_ws, size_t ws_size,
                              hipStream_t stream) {
    const float* x    = (const float*)d_in[0];
    const float* mask = (const float*)d_in[1];
    const float* ln_g = (const float*)d_in[2];
    const float* ln_b = (const float*)d_in[3];
    const float* w1   = (const float*)d_in[4];
    const float* b1   = (const float*)d_in[5];
    const float* w2   = (const float*)d_in[6];
    const float* b2   = (const float*)d_in[7];
    float* out = (float*)d_out;

    const size_t MB = 1024 * 1024;
    dim3 blk(256);

    if (ws_size >= 70 * MB) {
        char* w = (char*)d_ws;
        unsigned short* Acos = (unsigned short*)w;             // @0,  2.4 MB (dead after cos gemm)
        unsigned short* Xe   = (unsigned short*)(w + 4 * MB);  // @4,  17.8 MB (dead after cos gemm)
        unsigned short* t    = (unsigned short*)(w + 32 * MB); // @32, 32 MB
        unsigned short* h    = (unsigned short*)w;             // @0,  32 MB (over Acos+Xe after ln)
        unsigned short* W1t  = (unsigned short*)(w + 64 * MB); // 2 MB
        unsigned short* W2t  = (unsigned short*)(w + 66 * MB); // 2 MB
        float* F = (float*)d_out;                              // 37.75 MB scratch in d_out

        build_acos<<<dim3(MF), blk, 0, stream>>>(Acos);
        build_xe<<<dim3(8192 / 64, KF / 32), blk, 0, stream>>>(x, Xe);
        pack_wt<<<dim3(1024 / 64, 1024 / 32), blk, 0, stream>>>(w1, W1t);
        pack_wt<<<dim3(1024 / 64, 1024 / 32), blk, 0, stream>>>(w2, W2t);

        // F[s][n] = sum_t Acos[s][t] * Xe[n][t]   (scale folded into Acos)
        gemm_bt<0><<<dim3(8192 / 128, MF / 128), blk, 0, stream>>>(
            Acos, Xe, KF, KF, KF, 8192, nullptr, nullptr, F);
        // t = bf16(LayerNorm(x + F[mirror]))  — one F-row read per pair
        ln_pair<<<dim3(1025, BATCH), blk, 0, stream>>>(x, F, ln_g, ln_b, t);
        // h = bf16(gelu(t @ W1 + b1))
        gemm_bt<1><<<dim3(1024 / 128, ROWS / 128), blk, 0, stream>>>(
            t, W1t, 1024, 1024, 1024, 1024, b1, nullptr, h);
        // out = (h @ W2 + b2) * mask
        gemm_bt<2><<<dim3(1024 / 128, ROWS / 128), blk, 0, stream>>>(
            h, W2t, 1024, 1024, 1024, 1024, b2, mask, out);
    } else {
        // fp32 fallback (round-1 path)
        float* yf = (float*)d_ws;
        const size_t bufBytes = (size_t)ROWS * DIMD * sizeof(float);
        fft_cos_kernel<<<dim3(DIMD / BN, SEQ / BM, BATCH), blk, 0, stream>>>(x, yf);
        ln_kernel<<<dim3(ROWS), blk, 0, stream>>>(yf, ln_g, ln_b);
        ff_gemm<0><<<dim3(DIMD / BN, ROWS / BM), blk, 0, stream>>>(yf, w1, b1, nullptr, out);
        ff_gemm<1><<<dim3(DIMD / BN, ROWS / BM), blk, 0, stream>>>(out, w2, b2, mask, yf);
        hipMemcpyAsync(d_out, yf, bufBytes, hipMemcpyDeviceToDevice, stream);
    }
}